// Round 9
// baseline (71.006 us; speedup 1.0000x reference)
//
#include <hip/hip_runtime.h>

#define MM 576
#define NBLK 256    // 4n x 4t x 16s; 2 blocks/CU (LDS-limited), all co-resident
#define NTHR 512    // 8 waves: (g, tout); wave handles hd pair {2g, 2g+1}

__device__ __forceinline__ float lrelu(float x) { return x > 0.f ? x : 0.2f * x; }
__device__ __forceinline__ float elu1(float x)  { return x > 0.f ? x : (__expf(x) - 1.f); }
__device__ __forceinline__ unsigned short f2bf(float f) {   // RNE
    unsigned u = __float_as_uint(f);
    return (unsigned short)((u + 0x7FFFu + ((u >> 16) & 1u)) >> 16);
}
__device__ __forceinline__ float bf2f(unsigned short h) {
    return __uint_as_float(((unsigned)h) << 16);
}

// Agent-scope (device-coherent) 4B accesses for the only cross-block payload
// (epart). Grid barrier then needs no L2 writeback/invalidate.
__device__ __forceinline__ void gstore(float* p, float v) {
    __hip_atomic_store(p, v, __ATOMIC_RELAXED, __HIP_MEMORY_SCOPE_AGENT);
}
__device__ __forceinline__ float gload(const float* p) {
    return __hip_atomic_load(const_cast<float*>(p), __ATOMIC_RELAXED, __HIP_MEMORY_SCOPE_AGENT);
}

// Fence-free grid barrier (validated rounds 7-8).
__device__ __forceinline__ void grid_barrier(unsigned* cnt, unsigned target) {
    asm volatile("s_waitcnt vmcnt(0)" ::: "memory");
    __syncthreads();
    if (threadIdx.x == 0) {
        __hip_atomic_fetch_add(cnt, 1u, __ATOMIC_RELAXED, __HIP_MEMORY_SCOPE_AGENT);
        while (__hip_atomic_load(cnt, __ATOMIC_RELAXED, __HIP_MEMORY_SCOPE_AGENT) < target)
            __builtin_amdgcn_s_sleep(2);
    }
    __syncthreads();
}

struct SMem {
    unsigned short Whh[4][4][9][32];    // [hd][tt][r][v] bf16, 9216 B
    unsigned short adjh[4][1024];       // adjn per head, bf16, 8192 B
    float e[4][4][2][32];               // [hd][q][which][v], 4096 B
    // unionf, phase-disjoint lifetimes:
    //   [0,1152)        xb: x / inter 9-row slice (layer boundary)
    //   w*1024..+1024   attC[w]: adjn fp32 scratch (w<4) -> att^T -> C
    //   [4096,5120)     phase1 red scratch [sub16][wh2][v32]
    //   (4+tout)*1024   g=1 partial accumulators (<=320 floats each)
    float unionf[8192];                 // 32768 B
    float d12w[4][32];                  // 512 B
};                                      // 54784 B -> 2 blocks/CU

// ---------------------------------------------------------------------------
// Phase 1: block (n,t,s) owns rows m = t*144 + s*9 + [0,9).
// thread (sub,v): hd = sub&3, rows r0+{0,4,8}. Wh -> LDS bf16; separable
// logit partials -> epart (agent stores).
// ---------------------------------------------------------------------------
__device__ void phase1(int n, int t, int s,
                       const float* __restrict__ xin,
                       const float* __restrict__ mw_l,
                       const float* __restrict__ mb_l,
                       const float* __restrict__ a_l,
                       float* __restrict__ epart,
                       SMem& sm) {
    int tid = threadIdx.x;
    __syncthreads();    // prior phase done with union/Whh
    float* xb = sm.unionf;
    if (xin) {
        const float4* src = (const float4*)(xin + (size_t)(n * MM + t * 144 + s * 9) * 128);
        float4* dst = (float4*)xb;
        if (tid < 288) dst[tid] = src[tid];
    }
    __syncthreads();
    int sub = tid >> 5, v = tid & 31;
    int hd = sub & 3, r0 = sub >> 2;
    float ei = 0.f, ej = 0.f;
    for (int r = r0; r < 9; r += 4) {
        int rr = s * 9 + r;
        int dh = rr / 24, wc = rr % 24;
        const float* ab = a_l + hd * 1152 + dh * 192 + wc * 4;
        float4 aiv = *(const float4*)ab;
        float4 ajv = *(const float4*)(ab + 96);
        float x0 = xb[r * 128 + v],      x1 = xb[r * 128 + 32 + v];
        float x2 = xb[r * 128 + 64 + v], x3 = xb[r * 128 + 96 + v];
#pragma unroll
        for (int tt = 0; tt < 4; ++tt) {
            float wh = fmaf(x0, mw_l[hd * 16 + tt],
                        fmaf(x1, mw_l[hd * 16 + 4 + tt],
                         fmaf(x2, mw_l[hd * 16 + 8 + tt],
                          fmaf(x3, mw_l[hd * 16 + 12 + tt], mb_l[hd * 4 + tt]))));
            sm.Whh[hd][tt][r][v] = f2bf(wh);
            ei = fmaf(wh, (&aiv.x)[tt], ei);
            ej = fmaf(wh, (&ajv.x)[tt], ej);
        }
    }
    float* red = sm.unionf + 4096;      // [sub16][wh2][v32]
    red[(sub * 2 + 0) * 32 + v] = ei;
    red[(sub * 2 + 1) * 32 + v] = ej;
    __syncthreads();
    if (tid < 256) {        // tid == hd*64 + wh*32 + v
        int hdx = tid >> 6, whx = (tid >> 5) & 1, vx = tid & 31;
        float e = 0.f;
#pragma unroll
        for (int k = 0; k < 4; ++k)
            e += red[((hdx + 4 * k) * 2 + whx) * 32 + vx];
        gstore(&epart[(((size_t)(n * 4 + t) * 16 + s) << 8) + tid], e);
    }
}

// ---------------------------------------------------------------------------
// Phase 2+3: 8 waves. Wave (g,tout) computes hd in {2g, 2g+1}: att^T (linear
// store) -> C (in place) -> gemm 9 bf16 Wh rows (b128 reads, 5/4 row split).
// g=1 partials summed into g=0 via LDS. Layer 0 -> xb, layer 1 -> out.
// ---------------------------------------------------------------------------
__device__ void phase23(int n, int t, int s, int layer,
                        const float* __restrict__ Bp,
                        const float* __restrict__ epart,
                        float* __restrict__ outg,
                        SMem& sm) {
    int tid = threadIdx.x;
    int w = tid >> 6, lane = tid & 63;
    int g = w >> 2, tout = w & 3;
    int u = lane & 31, h = lane >> 5;
    float* attC = sm.unionf + w * 1024;

    {   // gather e over 16 s-slices: 512 threads cover (hd, qh, wh, v) x 2 q
        int hd = tid >> 7, rem = tid & 127;
        int qh = rem >> 6, wh = (rem >> 5) & 1, v = rem & 31;
        int le = hd * 64 + wh * 32 + v;
#pragma unroll
        for (int qq = 0; qq < 2; ++qq) {
            int q = qh * 2 + qq;
            float acc = 0.f;
#pragma unroll
            for (int ss = 0; ss < 16; ++ss)
                acc += gload(&epart[(((size_t)(n * 4 + q) * 16 + ss) << 8) + le]);
            sm.e[hd][q][wh][v] = acc;
        }
    }

    if (g == 0) {   // waves 0-3: build adjn for head tout (fp32 scratch in attC)
        const float* B = Bp + ((size_t)layer * 4 + tout) * 1024;
        float val[16];
        float lmin = 1e30f, lmax = -1e30f;
#pragma unroll
        for (int k = 0; k < 16; ++k) {
            int p = lane + 64 * k;
            float vv = B[p] + ((p >> 5) == (p & 31) ? 1.f : 0.f);
            val[k] = vv;
            lmin = fminf(lmin, vv);
            lmax = fmaxf(lmax, vv);
        }
#pragma unroll
        for (int off = 32; off; off >>= 1) {
            lmin = fminf(lmin, __shfl_xor(lmin, off, 64));
            lmax = fmaxf(lmax, __shfl_xor(lmax, off, 64));
        }
        float inv = 1.f / (lmax - lmin);
#pragma unroll
        for (int k = 0; k < 16; ++k) {
            val[k] = (val[k] - lmin) * inv;
            attC[lane + 64 * k] = val[k];
        }
        float rs = 0.f;     // row-sum of row u, rotated: conflict-free
#pragma unroll
        for (int jj = 0; jj < 16; ++jj) {
            int j_ = (jj + (h ? 16 : 0) + u) & 31;
            rs += attC[u * 32 + j_];
        }
        rs += __shfl_xor(rs, 32, 64);
        if (lane < 32) sm.d12w[tout][lane] = rsqrtf(rs);
#pragma unroll
        for (int k = 0; k < 16; ++k) {
            int p = lane + 64 * k;
            sm.adjh[tout][p] = f2bf(val[k] * sm.d12w[tout][p >> 5] * sm.d12w[tout][p & 31]);
        }
    }
    __syncthreads();    // e + all adjn ready

    float acc[5] = {0.f, 0.f, 0.f, 0.f, 0.f};

#pragma unroll 1
    for (int ii = 0; ii < 2; ++ii) {
        int hd = g * 2 + ii;
        // ---- att^T[j][i] at attC[j*32+i]; lane handles j=2k+h, i=u ----
        float ei0 = sm.e[hd][0][0][u], ei1 = sm.e[hd][1][0][u];
        float ei2 = sm.e[hd][2][0][u], ei3 = sm.e[hd][3][0][u];
#pragma unroll
        for (int k = 0; k < 16; ++k) {
            int j = 2 * k + h;
            float eq0 = lrelu(ei0 + sm.e[hd][0][1][j]);
            float eq1 = lrelu(ei1 + sm.e[hd][1][1][j]);
            float eq2 = lrelu(ei2 + sm.e[hd][2][1][j]);
            float eq3 = lrelu(ei3 + sm.e[hd][3][1][j]);
            float mx = fmaxf(fmaxf(eq0, eq1), fmaxf(eq2, eq3));
            eq0 = __expf(eq0 - mx); eq1 = __expf(eq1 - mx);
            eq2 = __expf(eq2 - mx); eq3 = __expf(eq3 - mx);
            float invs = __builtin_amdgcn_rcpf(eq0 + eq1 + eq2 + eq3);
            float num = (tout & 2) ? ((tout & 1) ? eq3 : eq2) : ((tout & 1) ? eq1 : eq0);
            attC[j * 32 + u] = num * invs;
        }
        // ---- adj column u (bf16, coalesced) ----
        float av[32];
#pragma unroll
        for (int i = 0; i < 32; ++i) av[i] = bf2f(sm.adjh[hd][i * 32 + u]);
        // ---- C[j][u] = dot(attT row j, av); rows broadcast per half ----
        float cloc[16];
#pragma unroll
        for (int k = 0; k < 16; ++k) {
            const float4* row = (const float4*)&attC[(h + 2 * k) * 32];
            float c = 0.f;
#pragma unroll
            for (int q4 = 0; q4 < 8; ++q4) {
                float4 a4 = row[q4];
                c = fmaf(a4.x, av[q4 * 4 + 0], c);
                c = fmaf(a4.y, av[q4 * 4 + 1], c);
                c = fmaf(a4.z, av[q4 * 4 + 2], c);
                c = fmaf(a4.w, av[q4 * 4 + 3], c);
            }
            cloc[k] = c;
        }
#pragma unroll
        for (int k = 0; k < 16; ++k) attC[(h + 2 * k) * 32 + u] = cloc[k];
        // ---- gemm: h=0 rows 0..4, h=1 rows 5..8; Wh rows as b128 ----
        float cc[32];
#pragma unroll
        for (int j = 0; j < 32; ++j) cc[j] = attC[j * 32 + u];
#pragma unroll
        for (int k = 0; k < 5; ++k) {
            int r = h ? (k < 4 ? 5 + k : 8) : k;   // clamp; k==4,h==1 discarded
            const uint4* wr = (const uint4*)&sm.Whh[hd][tout][r][0];
            float d = 0.f;
#pragma unroll
            for (int q4 = 0; q4 < 4; ++q4) {
                uint4 pk = wr[q4];
                d = fmaf(__uint_as_float(pk.x << 16),         cc[8 * q4 + 0], d);
                d = fmaf(__uint_as_float(pk.x & 0xFFFF0000u), cc[8 * q4 + 1], d);
                d = fmaf(__uint_as_float(pk.y << 16),         cc[8 * q4 + 2], d);
                d = fmaf(__uint_as_float(pk.y & 0xFFFF0000u), cc[8 * q4 + 3], d);
                d = fmaf(__uint_as_float(pk.z << 16),         cc[8 * q4 + 4], d);
                d = fmaf(__uint_as_float(pk.z & 0xFFFF0000u), cc[8 * q4 + 5], d);
                d = fmaf(__uint_as_float(pk.w << 16),         cc[8 * q4 + 6], d);
                d = fmaf(__uint_as_float(pk.w & 0xFFFF0000u), cc[8 * q4 + 7], d);
            }
            acc[k] += elu1(d);
        }
    }

    if (g == 1) {   // publish partials in own attC area (w = 4+tout)
#pragma unroll
        for (int k = 0; k < 5; ++k)
            if (h == 0 || k < 4) attC[k * 64 + lane] = acc[k];
    }
    __syncthreads();
    if (g == 0) {
        const float* part = sm.unionf + (4 + tout) * 1024;
#pragma unroll
        for (int k = 0; k < 5; ++k)
            if (h == 0 || k < 4) acc[k] += part[k * 64 + lane];
        if (layer == 0) {
            float* xb = sm.unionf;
#pragma unroll
            for (int k = 0; k < 5; ++k) {
                if (h == 0 || k < 4) {
                    int r = h ? 5 + k : k;
                    xb[r * 128 + tout * 32 + u] = 0.25f * acc[k];
                }
            }
        } else {
            size_t mb = (size_t)(n * MM + t * 144 + s * 9);
#pragma unroll
            for (int k = 0; k < 5; ++k) {
                if (h == 0 || k < 4) {
                    int r = h ? 5 + k : k;
                    outg[((mb + r) * 4 + tout) * 32 + u] = 0.25f * acc[k];
                }
            }
        }
    }
}

// ---------------------------------------------------------------------------
__global__ __launch_bounds__(NTHR, 4) void fused_kernel(const float* __restrict__ x,
                                                        const float* __restrict__ map_w,
                                                        const float* __restrict__ map_b,
                                                        const float* __restrict__ a_temp,
                                                        const float* __restrict__ Bp,
                                                        float* __restrict__ out,
                                                        float* __restrict__ ws,
                                                        unsigned* __restrict__ cnt) {
    __shared__ SMem sm;
    float* epart0 = ws;                 // 65536 floats
    float* epart1 = ws + 65536;         // 65536 floats
    int b = blockIdx.x;
    int n = b >> 6, t = (b >> 4) & 3, s = b & 15;

    phase1(n, t, s, x, map_w, map_b, a_temp, epart0, sm);
    grid_barrier(cnt, NBLK);
    phase23(n, t, s, 0, Bp, epart0, out, sm);
    phase1(n, t, s, nullptr, map_w + 64, map_b + 16, a_temp + 4608, epart1, sm);
    grid_barrier(cnt, 2 * NBLK);
    phase23(n, t, s, 1, Bp, epart1, out, sm);
}

// ---------------------------------------------------------------------------
extern "C" void kernel_launch(void* const* d_in, const int* in_sizes, int n_in,
                              void* d_out, int out_size, void* d_ws, size_t ws_size,
                              hipStream_t stream) {
    const float* x      = (const float*)d_in[0];
    const float* map_w  = (const float*)d_in[1];
    const float* map_b  = (const float*)d_in[2];
    const float* a_temp = (const float*)d_in[3];
    const float* Bp     = (const float*)d_in[4];
    float* out = (float*)d_out;
    float* ws  = (float*)d_ws;

    unsigned* cnt = (unsigned*)((char*)d_ws + (4 << 20));
    hipMemsetAsync(cnt, 0, 64, stream);
    fused_kernel<<<NBLK, NTHR, 0, stream>>>(x, map_w, map_b, a_temp, Bp, out, ws, cnt);
}

// Round 10
// 64.904 us; speedup vs baseline: 1.0940x; 1.0940x over previous
//
#include <hip/hip_runtime.h>

#define MM 576
#define NBLK 256    // 4n x 4t x 16s; 2 blocks/CU (LDS-limited), all co-resident
#define NTHR 512    // 8 waves: (g, tout); wave handles hd pair {2g, 2g+1}

__device__ __forceinline__ float lrelu(float x) { return x > 0.f ? x : 0.2f * x; }
__device__ __forceinline__ float elu1(float x)  { return x > 0.f ? x : (__expf(x) - 1.f); }
__device__ __forceinline__ unsigned short f2bf(float f) {   // RNE
    unsigned u = __float_as_uint(f);
    return (unsigned short)((u + 0x7FFFu + ((u >> 16) & 1u)) >> 16);
}
__device__ __forceinline__ float bf2f(unsigned short h) {
    return __uint_as_float(((unsigned)h) << 16);
}

// Agent-scope (device-coherent) load: reads the MALL coherence point, so it
// sees device-scope atomicAdd results without any L2 invalidate.
__device__ __forceinline__ float gload(const float* p) {
    return __hip_atomic_load(const_cast<float*>(p), __ATOMIC_RELAXED, __HIP_MEMORY_SCOPE_AGENT);
}

// Fence-free grid barrier (validated rounds 7-9). vmcnt(0) drains this
// wave's outstanding global atomics (atomicAdd is vmcnt-counted), so all
// e contributions are at the coherence point before arrival.
__device__ __forceinline__ void grid_barrier(unsigned* cnt, unsigned target) {
    asm volatile("s_waitcnt vmcnt(0)" ::: "memory");
    __syncthreads();
    if (threadIdx.x == 0) {
        __hip_atomic_fetch_add(cnt, 1u, __ATOMIC_RELAXED, __HIP_MEMORY_SCOPE_AGENT);
        while (__hip_atomic_load(cnt, __ATOMIC_RELAXED, __HIP_MEMORY_SCOPE_AGENT) < target)
            __builtin_amdgcn_s_sleep(2);
    }
    __syncthreads();
}

struct SMem {
    unsigned short Whh[4][4][9][32];    // [hd][tt][r][v] bf16, 9216 B
    unsigned short adjh[4][1024];       // adjn per head, bf16, 8192 B
    float e[4][4][2][32];               // [hd][q][which][v], 4096 B
    // unionf, phase-disjoint lifetimes:
    //   [0,1152)        xb: x / inter 9-row slice (layer boundary)
    //   (g*4+t')*1024   att^T buffers per (g-group, tout') -> C in place
    //   [4096,5120)     phase1 red scratch [sub16][wh2][v32]
    //   (4+tout)*1024   g=1 partial accumulators
    float unionf[8192];                 // 32768 B
    float d12w[4][32];                  // 512 B
};                                      // 54784 B -> 2 blocks/CU

// ---------------------------------------------------------------------------
// Phase 1: block (n,t,s) owns rows m = t*144 + s*9 + [0,9).
// Wh -> LDS bf16; separable logit partials -> e_glob via device atomicAdd
// (producer-side reduction: consumers then read the tiny final e directly).
// ---------------------------------------------------------------------------
__device__ void phase1(int n, int t, int s,
                       const float* __restrict__ xin,
                       const float* __restrict__ mw_l,
                       const float* __restrict__ mb_l,
                       const float* __restrict__ a_l,
                       float* __restrict__ eg,
                       SMem& sm) {
    int tid = threadIdx.x;
    __syncthreads();    // prior phase done with union/Whh
    float* xb = sm.unionf;
    if (xin) {
        const float4* src = (const float4*)(xin + (size_t)(n * MM + t * 144 + s * 9) * 128);
        float4* dst = (float4*)xb;
        if (tid < 288) dst[tid] = src[tid];
    }
    __syncthreads();
    int sub = tid >> 5, v = tid & 31;
    int hd = sub & 3, r0 = sub >> 2;
    float ei = 0.f, ej = 0.f;
    for (int r = r0; r < 9; r += 4) {
        int rr = s * 9 + r;
        int dh = rr / 24, wc = rr % 24;
        const float* ab = a_l + hd * 1152 + dh * 192 + wc * 4;
        float4 aiv = *(const float4*)ab;
        float4 ajv = *(const float4*)(ab + 96);
        float x0 = xb[r * 128 + v],      x1 = xb[r * 128 + 32 + v];
        float x2 = xb[r * 128 + 64 + v], x3 = xb[r * 128 + 96 + v];
#pragma unroll
        for (int tt = 0; tt < 4; ++tt) {
            float wh = fmaf(x0, mw_l[hd * 16 + tt],
                        fmaf(x1, mw_l[hd * 16 + 4 + tt],
                         fmaf(x2, mw_l[hd * 16 + 8 + tt],
                          fmaf(x3, mw_l[hd * 16 + 12 + tt], mb_l[hd * 4 + tt]))));
            sm.Whh[hd][tt][r][v] = f2bf(wh);
            ei = fmaf(wh, (&aiv.x)[tt], ei);
            ej = fmaf(wh, (&ajv.x)[tt], ej);
        }
    }
    float* red = sm.unionf + 4096;      // [sub16][wh2][v32]
    red[(sub * 2 + 0) * 32 + v] = ei;
    red[(sub * 2 + 1) * 32 + v] = ej;
    __syncthreads();
    if (tid < 256) {        // tid == hd*64 + wh*32 + v
        int hdx = tid >> 6;
        float e = 0.f;
#pragma unroll
        for (int k = 0; k < 4; ++k)
            e += red[((hdx + 4 * k) * 2) * 32 + (tid & 63) * 1 + ((tid & 63) >= 32 ? 0 : 0)];
        // NOTE: red layout is [sub][wh][v]; recompute cleanly:
        e = 0.f;
        int whx = (tid >> 5) & 1, vx = tid & 31;
#pragma unroll
        for (int k = 0; k < 4; ++k)
            e += red[((hdx + 4 * k) * 2 + whx) * 32 + vx];
        atomicAdd(&eg[((size_t)(n * 4 + hdx) * 4 + t) * 64 + (tid & 63)], e);
    }
}

// ---------------------------------------------------------------------------
// Phase 2+3: 8 waves (g, tout). Cooperative softmax: the 4 tout-waves of a
// g-group jointly fill the group's 4 att^T buffers (each wave does a
// j-quarter, computing the 4-exp softmax ONCE and storing all 4 numerators).
// Then per wave: C (in place) -> gemm 9 bf16 Wh rows. g=1 partials summed
// into g=0 via LDS. Layer 0 -> xb, layer 1 -> out.
// ---------------------------------------------------------------------------
__device__ void phase23(int n, int t, int s, int layer,
                        const float* __restrict__ Bp,
                        const float* __restrict__ eg,
                        float* __restrict__ outg,
                        SMem& sm) {
    int tid = threadIdx.x;
    int w = tid >> 6, lane = tid & 63;
    int g = w >> 2, tout = w & 3;
    int u = lane & 31, h = lane >> 5;
    float* attC = sm.unionf + w * 1024;

    {   // gather final e for this n: 1024 agent loads per block (2/thread)
        float* ef = &sm.e[0][0][0][0];
        const float* src = eg + (size_t)n * 1024;
        ef[tid]       = gload(&src[tid]);
        ef[tid + 512] = gload(&src[tid + 512]);
    }

    if (g == 0) {   // waves 0-3: build adjn for head tout (fp32 scratch in attC)
        const float* B = Bp + ((size_t)layer * 4 + tout) * 1024;
        float val[16];
        float lmin = 1e30f, lmax = -1e30f;
#pragma unroll
        for (int k = 0; k < 16; ++k) {
            int p = lane + 64 * k;
            float vv = B[p] + ((p >> 5) == (p & 31) ? 1.f : 0.f);
            val[k] = vv;
            lmin = fminf(lmin, vv);
            lmax = fmaxf(lmax, vv);
        }
#pragma unroll
        for (int off = 32; off; off >>= 1) {
            lmin = fminf(lmin, __shfl_xor(lmin, off, 64));
            lmax = fmaxf(lmax, __shfl_xor(lmax, off, 64));
        }
        float inv = 1.f / (lmax - lmin);
#pragma unroll
        for (int k = 0; k < 16; ++k) {
            val[k] = (val[k] - lmin) * inv;
            attC[lane + 64 * k] = val[k];
        }
        float rs = 0.f;     // row-sum of row u, rotated: conflict-free
#pragma unroll
        for (int jj = 0; jj < 16; ++jj) {
            int j_ = (jj + (h ? 16 : 0) + u) & 31;
            rs += attC[u * 32 + j_];
        }
        rs += __shfl_xor(rs, 32, 64);
        if (lane < 32) sm.d12w[tout][lane] = rsqrtf(rs);
#pragma unroll
        for (int k = 0; k < 16; ++k) {
            int p = lane + 64 * k;
            sm.adjh[tout][p] = f2bf(val[k] * sm.d12w[tout][p >> 5] * sm.d12w[tout][p & 31]);
        }
    }
    __syncthreads();    // e + all adjn ready

    float acc[5] = {0.f, 0.f, 0.f, 0.f, 0.f};
    float* Bg = sm.unionf + (size_t)(g * 4) * 1024;   // group's 4 att buffers

#pragma unroll 1
    for (int ii = 0; ii < 2; ++ii) {
        int hd = g * 2 + ii;
        // ---- cooperative att fill: this wave covers j = tout*8 + h + 2k ----
        float ei0 = sm.e[hd][0][0][u], ei1 = sm.e[hd][1][0][u];
        float ei2 = sm.e[hd][2][0][u], ei3 = sm.e[hd][3][0][u];
#pragma unroll
        for (int k = 0; k < 4; ++k) {
            int j = tout * 8 + h + 2 * k;
            float eq0 = lrelu(ei0 + sm.e[hd][0][1][j]);
            float eq1 = lrelu(ei1 + sm.e[hd][1][1][j]);
            float eq2 = lrelu(ei2 + sm.e[hd][2][1][j]);
            float eq3 = lrelu(ei3 + sm.e[hd][3][1][j]);
            float mx = fmaxf(fmaxf(eq0, eq1), fmaxf(eq2, eq3));
            eq0 = __expf(eq0 - mx); eq1 = __expf(eq1 - mx);
            eq2 = __expf(eq2 - mx); eq3 = __expf(eq3 - mx);
            float invs = __builtin_amdgcn_rcpf(eq0 + eq1 + eq2 + eq3);
            int off = j * 32 + u;
            Bg[off]        = eq0 * invs;
            Bg[1024 + off] = eq1 * invs;
            Bg[2048 + off] = eq2 * invs;
            Bg[3072 + off] = eq3 * invs;
        }
        __syncthreads();    // group's att buffers complete
        // ---- adj column u (bf16, coalesced) ----
        float av[32];
#pragma unroll
        for (int i = 0; i < 32; ++i) av[i] = bf2f(sm.adjh[hd][i * 32 + u]);
        // ---- C[j][u] = dot(attT row j, av); rows broadcast per half ----
        float cloc[16];
#pragma unroll
        for (int k = 0; k < 16; ++k) {
            const float4* row = (const float4*)&attC[(h + 2 * k) * 32];
            float c = 0.f;
#pragma unroll
            for (int q4 = 0; q4 < 8; ++q4) {
                float4 a4 = row[q4];
                c = fmaf(a4.x, av[q4 * 4 + 0], c);
                c = fmaf(a4.y, av[q4 * 4 + 1], c);
                c = fmaf(a4.z, av[q4 * 4 + 2], c);
                c = fmaf(a4.w, av[q4 * 4 + 3], c);
            }
            cloc[k] = c;
        }
#pragma unroll
        for (int k = 0; k < 16; ++k) attC[(h + 2 * k) * 32 + u] = cloc[k];
        // ---- gemm: h=0 rows 0..4, h=1 rows 5..8; Wh rows as b128 ----
        float cc[32];
#pragma unroll
        for (int j = 0; j < 32; ++j) cc[j] = attC[j * 32 + u];
#pragma unroll
        for (int k = 0; k < 5; ++k) {
            int r = h ? (k < 4 ? 5 + k : 8) : k;   // k==4,h==1 discarded
            const uint4* wr = (const uint4*)&sm.Whh[hd][tout][r][0];
            float d = 0.f;
#pragma unroll
            for (int q4 = 0; q4 < 4; ++q4) {
                uint4 pk = wr[q4];
                d = fmaf(__uint_as_float(pk.x << 16),         cc[8 * q4 + 0], d);
                d = fmaf(__uint_as_float(pk.x & 0xFFFF0000u), cc[8 * q4 + 1], d);
                d = fmaf(__uint_as_float(pk.y << 16),         cc[8 * q4 + 2], d);
                d = fmaf(__uint_as_float(pk.y & 0xFFFF0000u), cc[8 * q4 + 3], d);
                d = fmaf(__uint_as_float(pk.z << 16),         cc[8 * q4 + 4], d);
                d = fmaf(__uint_as_float(pk.z & 0xFFFF0000u), cc[8 * q4 + 5], d);
                d = fmaf(__uint_as_float(pk.w << 16),         cc[8 * q4 + 6], d);
                d = fmaf(__uint_as_float(pk.w & 0xFFFF0000u), cc[8 * q4 + 7], d);
            }
            acc[k] += elu1(d);
        }
        __syncthreads();    // att/C consumed; safe to refill next ii
    }

    if (g == 1) {   // publish partials in own attC area (w = 4+tout)
#pragma unroll
        for (int k = 0; k < 5; ++k)
            if (h == 0 || k < 4) attC[k * 64 + lane] = acc[k];
    }
    __syncthreads();
    if (g == 0) {
        const float* part = sm.unionf + (size_t)(4 + tout) * 1024;
#pragma unroll
        for (int k = 0; k < 5; ++k)
            if (h == 0 || k < 4) acc[k] += part[k * 64 + lane];
        if (layer == 0) {
            float* xb = sm.unionf;
#pragma unroll
            for (int k = 0; k < 5; ++k) {
                if (h == 0 || k < 4) {
                    int r = h ? 5 + k : k;
                    xb[r * 128 + tout * 32 + u] = 0.25f * acc[k];
                }
            }
        } else {
            size_t mb = (size_t)(n * MM + t * 144 + s * 9);
#pragma unroll
            for (int k = 0; k < 5; ++k) {
                if (h == 0 || k < 4) {
                    int r = h ? 5 + k : k;
                    outg[((mb + r) * 4 + tout) * 32 + u] = 0.25f * acc[k];
                }
            }
        }
    }
}

// ---------------------------------------------------------------------------
__global__ __launch_bounds__(NTHR, 4) void fused_kernel(const float* __restrict__ x,
                                                        const float* __restrict__ map_w,
                                                        const float* __restrict__ map_b,
                                                        const float* __restrict__ a_temp,
                                                        const float* __restrict__ Bp,
                                                        float* __restrict__ out,
                                                        float* __restrict__ ws,
                                                        unsigned* __restrict__ cnt) {
    __shared__ SMem sm;
    float* eg0 = ws;                    // 4096 floats (zeroed per launch)
    float* eg1 = ws + 4096;             // 4096 floats (zeroed per launch)
    int b = blockIdx.x;
    int n = b >> 6, t = (b >> 4) & 3, s = b & 15;

    phase1(n, t, s, x, map_w, map_b, a_temp, eg0, sm);
    grid_barrier(cnt, NBLK);
    phase23(n, t, s, 0, Bp, eg0, out, sm);
    phase1(n, t, s, nullptr, map_w + 64, map_b + 16, a_temp + 4608, eg1, sm);
    grid_barrier(cnt, 2 * NBLK);
    phase23(n, t, s, 1, Bp, eg1, out, sm);
}

// ---------------------------------------------------------------------------
extern "C" void kernel_launch(void* const* d_in, const int* in_sizes, int n_in,
                              void* d_out, int out_size, void* d_ws, size_t ws_size,
                              hipStream_t stream) {
    const float* x      = (const float*)d_in[0];
    const float* map_w  = (const float*)d_in[1];
    const float* map_b  = (const float*)d_in[2];
    const float* a_temp = (const float*)d_in[3];
    const float* Bp     = (const float*)d_in[4];
    float* out = (float*)d_out;
    float* ws  = (float*)d_ws;

    unsigned* cnt = (unsigned*)(ws + 8192);
    // zero e accumulators (2 x 16 KB) + barrier counter in one memset
    hipMemsetAsync(ws, 0, 8192 * 4 + 64, stream);
    fused_kernel<<<NBLK, NTHR, 0, stream>>>(x, map_w, map_b, a_temp, Bp, out, ws, cnt);
}

// Round 11
// 61.061 us; speedup vs baseline: 1.1629x; 1.0629x over previous
//
#include <hip/hip_runtime.h>

#define MM 576
#define NBLK 256    // 4n x 4t x 16s; 2 blocks/CU (LDS-limited), all co-resident
#define NTHR 512    // 8 waves: (g, tout); wave handles hd pair {2g, 2g+1}

__device__ __forceinline__ float lrelu(float x) { return x > 0.f ? x : 0.2f * x; }
__device__ __forceinline__ float elu1(float x)  { return x > 0.f ? x : (__expf(x) - 1.f); }
__device__ __forceinline__ unsigned short f2bf(float f) {   // RNE
    unsigned u = __float_as_uint(f);
    return (unsigned short)((u + 0x7FFFu + ((u >> 16) & 1u)) >> 16);
}
__device__ __forceinline__ float bf2f(unsigned short h) {
    return __uint_as_float(((unsigned)h) << 16);
}

// Agent-scope (device-coherent) load: sees device atomicAdd results at the
// coherence point without any L2 invalidate.
__device__ __forceinline__ float gload(const float* p) {
    return __hip_atomic_load(const_cast<float*>(p), __ATOMIC_RELAXED, __HIP_MEMORY_SCOPE_AGENT);
}

// Fence-free grid barrier (validated rounds 7-10). vmcnt(0) drains this
// wave's outstanding global atomics before arrival.
__device__ __forceinline__ void grid_barrier(unsigned* cnt, unsigned target) {
    asm volatile("s_waitcnt vmcnt(0)" ::: "memory");
    __syncthreads();
    if (threadIdx.x == 0) {
        __hip_atomic_fetch_add(cnt, 1u, __ATOMIC_RELAXED, __HIP_MEMORY_SCOPE_AGENT);
        while (__hip_atomic_load(cnt, __ATOMIC_RELAXED, __HIP_MEMORY_SCOPE_AGENT) < target)
            __builtin_amdgcn_s_sleep(2);
    }
    __syncthreads();
}

struct SMem {
    unsigned short Whh[4][4][9][32];    // [hd][tt][r][v] bf16, 9216 B
    unsigned short adjh[8][1024];       // [layer*4+hd][i*32+u] bf16, 16384 B
    float e[4][4][2][32];               // [hd][q][which][v], 4096 B
    union {                             // phase-disjoint lifetimes:
        unsigned short att[16][1024];   // [hd*4+q][j*32+i] bf16 numerators
        float f[8192];                  // f[0,1152): xb slice (layer boundary)
                                        // f[1216,2240): phase1 red scratch
                                        // f[2304,3584): g=1 partials [tout][320]
    } u;                                // 32768 B
};                                      // 62464 B -> 2 blocks/CU

// ---------------------------------------------------------------------------
// Adjacency pre-build: wave w (= layer*4+hd) builds one adjn, LDS-free via
// half-wave shfl row-sums (row 2k+h lives in the 32 lanes of half h).
// Runs once at kernel start, parallel with nothing on the critical path.
// ---------------------------------------------------------------------------
__device__ void adj_build(const float* __restrict__ Bp, SMem& sm,
                          float* __restrict__ d12s /*LDS [8][32]*/) {
    int tid = threadIdx.x;
    int w = tid >> 6, lane = tid & 63;
    int u = lane & 31, h = lane >> 5;
    const float* B = Bp + (size_t)w * 1024;
    float val[16];
    float lmin = 1e30f, lmax = -1e30f;
#pragma unroll
    for (int k = 0; k < 16; ++k) {
        int p = lane + 64 * k;
        float vv = B[p] + ((p >> 5) == (p & 31) ? 1.f : 0.f);
        val[k] = vv;
        lmin = fminf(lmin, vv);
        lmax = fmaxf(lmax, vv);
    }
#pragma unroll
    for (int off = 32; off; off >>= 1) {
        lmin = fminf(lmin, __shfl_xor(lmin, off, 64));
        lmax = fmaxf(lmax, __shfl_xor(lmax, off, 64));
    }
    float inv = 1.f / (lmax - lmin);
    float d12r[16];
#pragma unroll
    for (int k = 0; k < 16; ++k) {      // raw row sum of row 2k+h (half-wave)
        float r = val[k];
#pragma unroll
        for (int off = 16; off; off >>= 1) r += __shfl_xor(r, off, 64);
        float rsn = (r - 32.f * lmin) * inv;   // row sum of normalized adj
        d12r[k] = rsqrtf(rsn);
        if (u == 2 * k + h) d12s[w * 32 + u] = d12r[k];
    }
    float d12c = d12s[w * 32 + u];      // in-wave LDS write->read, ordered
#pragma unroll
    for (int k = 0; k < 16; ++k) {
        int p = lane + 64 * k;
        float vn = (val[k] - lmin) * inv;
        sm.adjh[w][p] = f2bf(vn * d12r[k] * d12c);
    }
}

// ---------------------------------------------------------------------------
// Phase 1: block (n,t,s) owns rows m = t*144 + s*9 + [0,9).
// Wh -> LDS bf16; separable logit partials -> eg via fire-and-forget atomics.
// ---------------------------------------------------------------------------
__device__ void phase1(int n, int t, int s,
                       const float* __restrict__ xin,
                       const float* __restrict__ mw_l,
                       const float* __restrict__ mb_l,
                       const float* __restrict__ a_l,
                       float* __restrict__ eg,
                       SMem& sm) {
    int tid = threadIdx.x;
    __syncthreads();    // prior phase done with union/Whh
    float* xb = sm.u.f;
    if (xin) {
        const float4* src = (const float4*)(xin + (size_t)(n * MM + t * 144 + s * 9) * 128);
        float4* dst = (float4*)xb;
        if (tid < 288) dst[tid] = src[tid];
    }
    __syncthreads();
    int sub = tid >> 5, v = tid & 31;
    int hd = sub & 3, r0 = sub >> 2;
    float ei = 0.f, ej = 0.f;
    for (int r = r0; r < 9; r += 4) {
        int rr = s * 9 + r;
        int dh = rr / 24, wc = rr % 24;
        const float* ab = a_l + hd * 1152 + dh * 192 + wc * 4;
        float4 aiv = *(const float4*)ab;
        float4 ajv = *(const float4*)(ab + 96);
        float x0 = xb[r * 128 + v],      x1 = xb[r * 128 + 32 + v];
        float x2 = xb[r * 128 + 64 + v], x3 = xb[r * 128 + 96 + v];
#pragma unroll
        for (int tt = 0; tt < 4; ++tt) {
            float wh = fmaf(x0, mw_l[hd * 16 + tt],
                        fmaf(x1, mw_l[hd * 16 + 4 + tt],
                         fmaf(x2, mw_l[hd * 16 + 8 + tt],
                          fmaf(x3, mw_l[hd * 16 + 12 + tt], mb_l[hd * 4 + tt]))));
            sm.Whh[hd][tt][r][v] = f2bf(wh);
            ei = fmaf(wh, (&aiv.x)[tt], ei);
            ej = fmaf(wh, (&ajv.x)[tt], ej);
        }
    }
    float* red = sm.u.f + 1216;         // [sub16][wh2][v32]
    red[(sub * 2 + 0) * 32 + v] = ei;
    red[(sub * 2 + 1) * 32 + v] = ej;
    __syncthreads();
    if (tid < 256) {        // tid == hd*64 + wh*32 + v
        int hdx = tid >> 6, whx = (tid >> 5) & 1, vx = tid & 31;
        float e = 0.f;
#pragma unroll
        for (int k = 0; k < 4; ++k)
            e += red[((hdx + 4 * k) * 2 + whx) * 32 + vx];
        atomicAdd(&eg[((size_t)(n * 4 + hdx) * 4 + t) * 64 + (tid & 63)], e);
    }
}

// ---------------------------------------------------------------------------
// Phase 2+3: e-gather -> single cooperative att fill (all 16 bf16 buffers,
// one sync) -> per wave: C fp32 (shfl_xor redistribute, no LDS round trip)
// -> gemm. g=1 partials exchanged at the end. Layer 0 -> xb, layer 1 -> out.
// ---------------------------------------------------------------------------
__device__ void phase23(int n, int t, int s, int layer,
                        const float* __restrict__ eg,
                        float* __restrict__ outg,
                        SMem& sm) {
    int tid = threadIdx.x;
    int w = tid >> 6, lane = tid & 63;
    int g = w >> 2, tout = w & 3;
    int u = lane & 31, h = lane >> 5;

    {   // gather final e for this n: 1024 agent loads per block (2/thread)
        float* ef = &sm.e[0][0][0][0];
        const float* src = eg + (size_t)n * 1024;
        ef[tid]       = gload(&src[tid]);
        ef[tid + 512] = gload(&src[tid + 512]);
    }
    __syncthreads();

    // ---- cooperative att fill: wave (g,tout) covers j = tout*8 + h + 2k
    //      for both hd of its group; stores all 4 tout-numerators (bf16) ----
#pragma unroll
    for (int ii = 0; ii < 2; ++ii) {
        int hd = g * 2 + ii;
        float ei0 = sm.e[hd][0][0][u], ei1 = sm.e[hd][1][0][u];
        float ei2 = sm.e[hd][2][0][u], ei3 = sm.e[hd][3][0][u];
#pragma unroll
        for (int k = 0; k < 4; ++k) {
            int j = tout * 8 + h + 2 * k;
            float eq0 = lrelu(ei0 + sm.e[hd][0][1][j]);
            float eq1 = lrelu(ei1 + sm.e[hd][1][1][j]);
            float eq2 = lrelu(ei2 + sm.e[hd][2][1][j]);
            float eq3 = lrelu(ei3 + sm.e[hd][3][1][j]);
            float mx = fmaxf(fmaxf(eq0, eq1), fmaxf(eq2, eq3));
            eq0 = __expf(eq0 - mx); eq1 = __expf(eq1 - mx);
            eq2 = __expf(eq2 - mx); eq3 = __expf(eq3 - mx);
            float invs = __builtin_amdgcn_rcpf(eq0 + eq1 + eq2 + eq3);
            int off = j * 32 + u;
            sm.u.att[hd * 4 + 0][off] = f2bf(eq0 * invs);
            sm.u.att[hd * 4 + 1][off] = f2bf(eq1 * invs);
            sm.u.att[hd * 4 + 2][off] = f2bf(eq2 * invs);
            sm.u.att[hd * 4 + 3][off] = f2bf(eq3 * invs);
        }
    }
    __syncthreads();    // all 16 att buffers complete

    float acc[5] = {0.f, 0.f, 0.f, 0.f, 0.f};

#pragma unroll 1
    for (int ii = 0; ii < 2; ++ii) {
        int hd = g * 2 + ii;
        // ---- adj column u (bf16 scalar reads, 2 lanes/bank = free) ----
        float av[32];
#pragma unroll
        for (int i = 0; i < 32; ++i) av[i] = bf2f(sm.adjh[layer * 4 + hd][i * 32 + u]);
        // ---- C[h+2k][u] = dot(att^T row, av); rows broadcast per half ----
        const unsigned short* ab = sm.u.att[hd * 4 + tout];
        float cloc[16];
#pragma unroll
        for (int k = 0; k < 16; ++k) {
            const uint4* r4 = (const uint4*)&ab[(h + 2 * k) * 32];
            float c = 0.f;
#pragma unroll
            for (int q4 = 0; q4 < 4; ++q4) {
                uint4 pk = r4[q4];
                c = fmaf(__uint_as_float(pk.x << 16),         av[8 * q4 + 0], c);
                c = fmaf(__uint_as_float(pk.x & 0xFFFF0000u), av[8 * q4 + 1], c);
                c = fmaf(__uint_as_float(pk.y << 16),         av[8 * q4 + 2], c);
                c = fmaf(__uint_as_float(pk.y & 0xFFFF0000u), av[8 * q4 + 3], c);
                c = fmaf(__uint_as_float(pk.z << 16),         av[8 * q4 + 4], c);
                c = fmaf(__uint_as_float(pk.z & 0xFFFF0000u), av[8 * q4 + 5], c);
                c = fmaf(__uint_as_float(pk.w << 16),         av[8 * q4 + 6], c);
                c = fmaf(__uint_as_float(pk.w & 0xFFFF0000u), av[8 * q4 + 7], c);
            }
            cloc[k] = c;
        }
        // ---- redistribute C across halves via shfl (no LDS round trip) ----
        float cc[32];
#pragma unroll
        for (int k = 0; k < 16; ++k) {
            float other = __shfl_xor(cloc[k], 32, 64);
            cc[2 * k]     = h ? other   : cloc[k];
            cc[2 * k + 1] = h ? cloc[k] : other;
        }
        // ---- gemm: h=0 rows 0..4, h=1 rows 5..8; Wh rows as b128 ----
#pragma unroll
        for (int k = 0; k < 5; ++k) {
            int r = h ? (k < 4 ? 5 + k : 8) : k;   // k==4,h==1 discarded
            const uint4* wr = (const uint4*)&sm.Whh[hd][tout][r][0];
            float d = 0.f;
#pragma unroll
            for (int q4 = 0; q4 < 4; ++q4) {
                uint4 pk = wr[q4];
                d = fmaf(__uint_as_float(pk.x << 16),         cc[8 * q4 + 0], d);
                d = fmaf(__uint_as_float(pk.x & 0xFFFF0000u), cc[8 * q4 + 1], d);
                d = fmaf(__uint_as_float(pk.y << 16),         cc[8 * q4 + 2], d);
                d = fmaf(__uint_as_float(pk.y & 0xFFFF0000u), cc[8 * q4 + 3], d);
                d = fmaf(__uint_as_float(pk.z << 16),         cc[8 * q4 + 4], d);
                d = fmaf(__uint_as_float(pk.z & 0xFFFF0000u), cc[8 * q4 + 5], d);
                d = fmaf(__uint_as_float(pk.w << 16),         cc[8 * q4 + 6], d);
                d = fmaf(__uint_as_float(pk.w & 0xFFFF0000u), cc[8 * q4 + 7], d);
            }
            acc[k] += elu1(d);
        }
    }

    __syncthreads();    // att fully consumed by all waves
    if (g == 1) {       // publish partials into dead att region
        float* part = sm.u.f + 2304 + tout * 320;
#pragma unroll
        for (int k = 0; k < 5; ++k)
            if (h == 0 || k < 4) part[k * 64 + lane] = acc[k];
    }
    __syncthreads();
    if (g == 0) {
        const float* part = sm.u.f + 2304 + tout * 320;
#pragma unroll
        for (int k = 0; k < 5; ++k)
            if (h == 0 || k < 4) acc[k] += part[k * 64 + lane];
        if (layer == 0) {
            float* xb = sm.u.f;
#pragma unroll
            for (int k = 0; k < 5; ++k) {
                if (h == 0 || k < 4) {
                    int r = h ? 5 + k : k;
                    xb[r * 128 + tout * 32 + u] = 0.25f * acc[k];
                }
            }
        } else {
            size_t mb = (size_t)(n * MM + t * 144 + s * 9);
#pragma unroll
            for (int k = 0; k < 5; ++k) {
                if (h == 0 || k < 4) {
                    int r = h ? 5 + k : k;
                    outg[((mb + r) * 4 + tout) * 32 + u] = 0.25f * acc[k];
                }
            }
        }
    }
}

// ---------------------------------------------------------------------------
__global__ __launch_bounds__(NTHR, 4) void fused_kernel(const float* __restrict__ x,
                                                        const float* __restrict__ map_w,
                                                        const float* __restrict__ map_b,
                                                        const float* __restrict__ a_temp,
                                                        const float* __restrict__ Bp,
                                                        float* __restrict__ out,
                                                        float* __restrict__ ws,
                                                        unsigned* __restrict__ cnt) {
    __shared__ SMem sm;
    __shared__ float d12s[8][32];
    float* eg0 = ws;                    // 4096 floats (zeroed per launch)
    float* eg1 = ws + 4096;             // 4096 floats (zeroed per launch)
    int b = blockIdx.x;
    int n = b >> 6, t = (b >> 4) & 3, s = b & 15;

    adj_build(Bp, sm, &d12s[0][0]);     // both layers, all heads, off the path
    phase1(n, t, s, x, map_w, map_b, a_temp, eg0, sm);
    grid_barrier(cnt, NBLK);
    phase23(n, t, s, 0, eg0, out, sm);
    phase1(n, t, s, nullptr, map_w + 64, map_b + 16, a_temp + 4608, eg1, sm);
    grid_barrier(cnt, 2 * NBLK);
    phase23(n, t, s, 1, eg1, out, sm);
}

// ---------------------------------------------------------------------------
extern "C" void kernel_launch(void* const* d_in, const int* in_sizes, int n_in,
                              void* d_out, int out_size, void* d_ws, size_t ws_size,
                              hipStream_t stream) {
    const float* x      = (const float*)d_in[0];
    const float* map_w  = (const float*)d_in[1];
    const float* map_b  = (const float*)d_in[2];
    const float* a_temp = (const float*)d_in[3];
    const float* Bp     = (const float*)d_in[4];
    float* out = (float*)d_out;
    float* ws  = (float*)d_ws;

    unsigned* cnt = (unsigned*)(ws + 8192);
    // zero e accumulators (2 x 16 KB) + barrier counter in one memset
    hipMemsetAsync(ws, 0, 8192 * 4 + 64, stream);
    fused_kernel<<<NBLK, NTHR, 0, stream>>>(x, map_w, map_b, a_temp, Bp, out, ws, cnt);
}

// Round 12
// 47.272 us; speedup vs baseline: 1.5021x; 1.2917x over previous
//
#include <hip/hip_runtime.h>

#define MM 576
#define NBLK 256    // 4n x 4t x 16s
#define NTHR 512    // 8 waves

__device__ __forceinline__ float lrelu(float x) { return x > 0.f ? x : 0.2f * x; }
__device__ __forceinline__ float elu1(float x)  { return x > 0.f ? x : (__expf(x) - 1.f); }
__device__ __forceinline__ unsigned short f2bf(float f) {   // RNE
    unsigned u = __float_as_uint(f);
    return (unsigned short)((u + 0x7FFFu + ((u >> 16) & 1u)) >> 16);
}
__device__ __forceinline__ float bf2f(unsigned short h) {
    return __uint_as_float(((unsigned)h) << 16);
}

struct SMemK {
    unsigned short Whh[4][4][9][32];    // [hd][tt][r][v] bf16, 9216 B
    unsigned short adjh[4][1024];       // this layer's 4 heads, bf16, 8192 B
    float e[4][4][2][32];               // [hd][q][which][v], 4096 B
    union {                             // phase-disjoint lifetimes:
        unsigned short att[16][1024];   // [hd*4+q][j*32+i] bf16 numerators
        float f[8192];                  // f[0,1152): xb (inter rows, K2 tail)
                                        // f[1216,2240): tail red scratch
                                        // f[2304,3584): g=1 partials
    } u;                                // 32768 B
    float d12s[4][32];                  // 512 B
};                                      // 54784 B -> 2 blocks/CU

// ---------------------------------------------------------------------------
// Wh + e-partial producer body (shared by K1 and K2's tail).
// Block (n,t,s) owns rows m = t*144 + s*9 + [0,9).  Wh -> Whg[b*4608]
// (bf16, block-contiguous); e-partials -> ep[n][q=t][s][256] (plain stores).
// ---------------------------------------------------------------------------
__device__ __forceinline__ void wh_e_body(int n, int t, int s, int b,
                                          const float* __restrict__ xb,   // LDS
                                          float* __restrict__ red,        // LDS
                                          const float* __restrict__ mw_l,
                                          const float* __restrict__ mb_l,
                                          const float* __restrict__ a_l,
                                          unsigned short* __restrict__ Whg,
                                          float* __restrict__ ep) {
    int tid = threadIdx.x;
    int sub = tid >> 5, v = tid & 31;
    int hd = sub & 3, r0 = sub >> 2;
    unsigned short* Wb = Whg + (size_t)b * 4608;
    float ei = 0.f, ej = 0.f;
    for (int r = r0; r < 9; r += 4) {
        int rr = s * 9 + r;
        int dh = rr / 24, wc = rr % 24;
        const float* ab = a_l + hd * 1152 + dh * 192 + wc * 4;
        float4 aiv = *(const float4*)ab;
        float4 ajv = *(const float4*)(ab + 96);
        float x0 = xb[r * 128 + v],      x1 = xb[r * 128 + 32 + v];
        float x2 = xb[r * 128 + 64 + v], x3 = xb[r * 128 + 96 + v];
#pragma unroll
        for (int tt = 0; tt < 4; ++tt) {
            float wh = fmaf(x0, mw_l[hd * 16 + tt],
                        fmaf(x1, mw_l[hd * 16 + 4 + tt],
                         fmaf(x2, mw_l[hd * 16 + 8 + tt],
                          fmaf(x3, mw_l[hd * 16 + 12 + tt], mb_l[hd * 4 + tt]))));
            Wb[((hd * 4 + tt) * 9 + r) * 32 + v] = f2bf(wh);
            ei = fmaf(wh, (&aiv.x)[tt], ei);
            ej = fmaf(wh, (&ajv.x)[tt], ej);
        }
    }
    red[(sub * 2 + 0) * 32 + v] = ei;
    red[(sub * 2 + 1) * 32 + v] = ej;
    __syncthreads();
    if (tid < 256) {        // tid == hd*64 + wh*32 + v
        int hdx = tid >> 6, whx = (tid >> 5) & 1, vx = tid & 31;
        float e = 0.f;
#pragma unroll
        for (int k = 0; k < 4; ++k)
            e += red[((hdx + 4 * k) * 2 + whx) * 32 + vx];
        ep[(((size_t)(n * 4 + t)) * 16 + s) * 256 + tid] = e;
    }
}

// ---------------------------------------------------------------------------
// K1: stage x slice -> Wh(L0) + e-partials(L0).
// ---------------------------------------------------------------------------
__global__ __launch_bounds__(NTHR) void k1(const float* __restrict__ x,
                                           const float* __restrict__ map_w,
                                           const float* __restrict__ map_b,
                                           const float* __restrict__ a_temp,
                                           unsigned short* __restrict__ Whg,
                                           float* __restrict__ ep0) {
    __shared__ float xb[1152];
    __shared__ float red[1024];
    int b = blockIdx.x, tid = threadIdx.x;
    int n = b >> 6, t = (b >> 4) & 3, s = b & 15;
    if (tid < 288)
        ((float4*)xb)[tid] =
            ((const float4*)(x + (size_t)(n * MM + t * 144 + s * 9) * 128))[tid];
    __syncthreads();
    wh_e_body(n, t, s, b, xb, red, map_w, map_b, a_temp, Whg, ep0);
}

// ---------------------------------------------------------------------------
// Adjacency build for this layer's 4 heads: wave w (<4) builds head w.
// Half-wave shfl row-sums, LDS-free except the tiny d12 exchange.
// ---------------------------------------------------------------------------
__device__ __forceinline__ void adj_build4(const float* __restrict__ Bp_l, SMemK& sm) {
    int tid = threadIdx.x;              // caller guarantees tid < 256
    int w = tid >> 6, lane = tid & 63;
    int u = lane & 31, h = lane >> 5;
    const float* B = Bp_l + (size_t)w * 1024;
    float val[16];
    float lmin = 1e30f, lmax = -1e30f;
#pragma unroll
    for (int k = 0; k < 16; ++k) {
        int p = lane + 64 * k;
        float vv = B[p] + ((p >> 5) == (p & 31) ? 1.f : 0.f);
        val[k] = vv;
        lmin = fminf(lmin, vv);
        lmax = fmaxf(lmax, vv);
    }
#pragma unroll
    for (int off = 32; off; off >>= 1) {
        lmin = fminf(lmin, __shfl_xor(lmin, off, 64));
        lmax = fmaxf(lmax, __shfl_xor(lmax, off, 64));
    }
    float inv = 1.f / (lmax - lmin);
    float d12r[16];
#pragma unroll
    for (int k = 0; k < 16; ++k) {      // row sum of row 2k+h (half-wave)
        float r = val[k];
#pragma unroll
        for (int off = 16; off; off >>= 1) r += __shfl_xor(r, off, 64);
        float rsn = (r - 32.f * lmin) * inv;
        d12r[k] = rsqrtf(rsn);
        if (u == 2 * k + h) sm.d12s[w][u] = d12r[k];
    }
    float d12c = sm.d12s[w][u];         // in-wave LDS write->read, ordered
#pragma unroll
    for (int k = 0; k < 16; ++k) {
        int p = lane + 64 * k;
        float vn = (val[k] - lmin) * inv;
        sm.adjh[w][p] = f2bf(vn * d12r[k] * d12c);
    }
}

// ---------------------------------------------------------------------------
// K2/K3 body: e-gather (all waves) -> {adj build | Whh copy} -> att fill ->
// C (shfl redistribute) -> gemm -> partial exchange. LAST ? out : (xb ->
// layer-2 Wh + e-partials, all block-local).
// ---------------------------------------------------------------------------
template<bool LAST>
__device__ void k23_body(const float* __restrict__ Bp_l,
                         const float* __restrict__ ep_in,
                         unsigned short* __restrict__ Whg,
                         const float* __restrict__ mw2,
                         const float* __restrict__ mb2,
                         const float* __restrict__ a2,
                         float* __restrict__ ep_out,
                         float* __restrict__ outg,
                         SMemK& sm) {
    int b = blockIdx.x, tid = threadIdx.x;
    int n = b >> 6, t = (b >> 4) & 3, s = b & 15;
    int w = tid >> 6, lane = tid & 63;
    int g = w >> 2, tout = w & 3;
    int u = lane & 31, h = lane >> 5;

    {   // ---- e-gather: cached loads, 2 final values per thread ----
        float* ef = &sm.e[0][0][0][0];
#pragma unroll
        for (int half = 0; half < 2; ++half) {
            int f = tid + half * 512;
            int hd = f >> 8, q = (f >> 6) & 3;
            const float* src = ep_in + ((size_t)(n * 4 + q) * 16) * 256 + hd * 64 + (f & 63);
            float acc = 0.f;
#pragma unroll
            for (int ss = 0; ss < 16; ++ss) acc += src[ss * 256];
            ef[f] = acc;
        }
    }
    // ---- waves 0-3: adjacency; waves 4-7: copy own Wh rows to LDS ----
    if (w < 4) {
        adj_build4(Bp_l, sm);
    } else {
        const unsigned* src = (const unsigned*)(Whg + (size_t)b * 4608);
        unsigned* dst = (unsigned*)&sm.Whh[0][0][0][0];
        int t0 = tid - 256;
#pragma unroll
        for (int k = 0; k < 9; ++k) dst[t0 + 256 * k] = src[t0 + 256 * k];
    }
    __syncthreads();

    // ---- cooperative att fill: wave (g,tout) covers j = tout*8 + h + 2k
    //      for both hd of its group; stores all 4 q-numerators (bf16) ----
#pragma unroll
    for (int ii = 0; ii < 2; ++ii) {
        int hd = g * 2 + ii;
        float ei0 = sm.e[hd][0][0][u], ei1 = sm.e[hd][1][0][u];
        float ei2 = sm.e[hd][2][0][u], ei3 = sm.e[hd][3][0][u];
#pragma unroll
        for (int k = 0; k < 4; ++k) {
            int j = tout * 8 + h + 2 * k;
            float eq0 = lrelu(ei0 + sm.e[hd][0][1][j]);
            float eq1 = lrelu(ei1 + sm.e[hd][1][1][j]);
            float eq2 = lrelu(ei2 + sm.e[hd][2][1][j]);
            float eq3 = lrelu(ei3 + sm.e[hd][3][1][j]);
            float mx = fmaxf(fmaxf(eq0, eq1), fmaxf(eq2, eq3));
            eq0 = __expf(eq0 - mx); eq1 = __expf(eq1 - mx);
            eq2 = __expf(eq2 - mx); eq3 = __expf(eq3 - mx);
            float invs = __builtin_amdgcn_rcpf(eq0 + eq1 + eq2 + eq3);
            int off = j * 32 + u;
            sm.u.att[hd * 4 + 0][off] = f2bf(eq0 * invs);
            sm.u.att[hd * 4 + 1][off] = f2bf(eq1 * invs);
            sm.u.att[hd * 4 + 2][off] = f2bf(eq2 * invs);
            sm.u.att[hd * 4 + 3][off] = f2bf(eq3 * invs);
        }
    }
    __syncthreads();

    float acc[5] = {0.f, 0.f, 0.f, 0.f, 0.f};
#pragma unroll 1
    for (int ii = 0; ii < 2; ++ii) {
        int hd = g * 2 + ii;
        float av[32];
#pragma unroll
        for (int i = 0; i < 32; ++i) av[i] = bf2f(sm.adjh[hd][i * 32 + u]);
        const unsigned short* ab = sm.u.att[hd * 4 + tout];
        float cloc[16];
#pragma unroll
        for (int k = 0; k < 16; ++k) {
            const uint4* r4 = (const uint4*)&ab[(h + 2 * k) * 32];
            float c = 0.f;
#pragma unroll
            for (int q4 = 0; q4 < 4; ++q4) {
                uint4 pk = r4[q4];
                c = fmaf(__uint_as_float(pk.x << 16),         av[8 * q4 + 0], c);
                c = fmaf(__uint_as_float(pk.x & 0xFFFF0000u), av[8 * q4 + 1], c);
                c = fmaf(__uint_as_float(pk.y << 16),         av[8 * q4 + 2], c);
                c = fmaf(__uint_as_float(pk.y & 0xFFFF0000u), av[8 * q4 + 3], c);
                c = fmaf(__uint_as_float(pk.z << 16),         av[8 * q4 + 4], c);
                c = fmaf(__uint_as_float(pk.z & 0xFFFF0000u), av[8 * q4 + 5], c);
                c = fmaf(__uint_as_float(pk.w << 16),         av[8 * q4 + 6], c);
                c = fmaf(__uint_as_float(pk.w & 0xFFFF0000u), av[8 * q4 + 7], c);
            }
            cloc[k] = c;
        }
        float cc[32];
#pragma unroll
        for (int k = 0; k < 16; ++k) {
            float other = __shfl_xor(cloc[k], 32, 64);
            cc[2 * k]     = h ? other   : cloc[k];
            cc[2 * k + 1] = h ? cloc[k] : other;
        }
#pragma unroll
        for (int k = 0; k < 5; ++k) {
            int r = h ? (k < 4 ? 5 + k : 8) : k;   // k==4,h==1 discarded
            const uint4* wr = (const uint4*)&sm.Whh[hd][tout][r][0];
            float d = 0.f;
#pragma unroll
            for (int q4 = 0; q4 < 4; ++q4) {
                uint4 pk = wr[q4];
                d = fmaf(__uint_as_float(pk.x << 16),         cc[8 * q4 + 0], d);
                d = fmaf(__uint_as_float(pk.x & 0xFFFF0000u), cc[8 * q4 + 1], d);
                d = fmaf(__uint_as_float(pk.y << 16),         cc[8 * q4 + 2], d);
                d = fmaf(__uint_as_float(pk.y & 0xFFFF0000u), cc[8 * q4 + 3], d);
                d = fmaf(__uint_as_float(pk.z << 16),         cc[8 * q4 + 4], d);
                d = fmaf(__uint_as_float(pk.z & 0xFFFF0000u), cc[8 * q4 + 5], d);
                d = fmaf(__uint_as_float(pk.w << 16),         cc[8 * q4 + 6], d);
                d = fmaf(__uint_as_float(pk.w & 0xFFFF0000u), cc[8 * q4 + 7], d);
            }
            acc[k] += elu1(d);
        }
    }

    __syncthreads();    // att fully consumed
    if (g == 1) {       // publish partials into dead att region
        float* part = sm.u.f + 2304 + tout * 320;
#pragma unroll
        for (int k = 0; k < 5; ++k)
            if (h == 0 || k < 4) part[k * 64 + lane] = acc[k];
    }
    __syncthreads();
    if (g == 0) {
        const float* part = sm.u.f + 2304 + tout * 320;
#pragma unroll
        for (int k = 0; k < 5; ++k)
            if (h == 0 || k < 4) acc[k] += part[k * 64 + lane];
        if (LAST) {
            size_t mb = (size_t)(n * MM + t * 144 + s * 9);
#pragma unroll
            for (int k = 0; k < 5; ++k) {
                if (h == 0 || k < 4) {
                    int r = h ? 5 + k : k;
                    outg[((mb + r) * 4 + tout) * 32 + u] = 0.25f * acc[k];
                }
            }
        } else {
            float* xb = sm.u.f;
#pragma unroll
            for (int k = 0; k < 5; ++k) {
                if (h == 0 || k < 4) {
                    int r = h ? 5 + k : k;
                    xb[r * 128 + tout * 32 + u] = 0.25f * acc[k];
                }
            }
        }
    }

    if (!LAST) {        // ---- layer-2 producer, entirely block-local ----
        __syncthreads();    // xb complete
        wh_e_body(n, t, s, b, sm.u.f, sm.u.f + 1216, mw2, mb2, a2, Whg, ep_out);
    }
}

__global__ __launch_bounds__(NTHR) void k2(const float* __restrict__ Bp,
                                           const float* __restrict__ ep0,
                                           unsigned short* __restrict__ Whg,
                                           const float* __restrict__ map_w,
                                           const float* __restrict__ map_b,
                                           const float* __restrict__ a_temp,
                                           float* __restrict__ ep1) {
    __shared__ SMemK sm;
    k23_body<false>(Bp, ep0, Whg, map_w + 64, map_b + 16, a_temp + 4608,
                    ep1, nullptr, sm);
}

__global__ __launch_bounds__(NTHR) void k3(const float* __restrict__ Bp,
                                           const float* __restrict__ ep1,
                                           unsigned short* __restrict__ Whg,
                                           float* __restrict__ outg) {
    __shared__ SMemK sm;
    k23_body<true>(Bp + 4096, ep1, Whg, nullptr, nullptr, nullptr,
                   nullptr, outg, sm);
}

// ---------------------------------------------------------------------------
extern "C" void kernel_launch(void* const* d_in, const int* in_sizes, int n_in,
                              void* d_out, int out_size, void* d_ws, size_t ws_size,
                              hipStream_t stream) {
    const float* x      = (const float*)d_in[0];
    const float* map_w  = (const float*)d_in[1];
    const float* map_b  = (const float*)d_in[2];
    const float* a_temp = (const float*)d_in[3];
    const float* Bp     = (const float*)d_in[4];
    float* out = (float*)d_out;

    unsigned short* Whg = (unsigned short*)d_ws;            // 256*4608 bf16 = 2.36 MB
    float* ep0 = (float*)((char*)d_ws + 2359296);           // 65536 floats
    float* ep1 = ep0 + 65536;                               // 65536 floats
    // Every byte of Whg/ep0/ep1 is overwritten before it is read each call:
    // no memset, no atomics, no barriers — coherence via kernel boundaries.

    k1<<<NBLK, NTHR, 0, stream>>>(x, map_w, map_b, a_temp, Whg, ep0);
    k2<<<NBLK, NTHR, 0, stream>>>(Bp, ep0, Whg, map_w, map_b, a_temp, ep1);
    k3<<<NBLK, NTHR, 0, stream>>>(Bp, ep1, Whg, out);
}

// Round 13
// 36.944 us; speedup vs baseline: 1.9220x; 1.2796x over previous
//
#include <hip/hip_runtime.h>

#define MM 576
#define NBLK 256
#define NTHR 512

__device__ __forceinline__ float lrelu(float x) { return x > 0.f ? x : 0.2f * x; }
__device__ __forceinline__ float elu1(float x)  { return x > 0.f ? x : (__expf(x) - 1.f); }
__device__ __forceinline__ unsigned short f2bf(float f) {   // RNE
    unsigned u = __float_as_uint(f);
    return (unsigned short)((u + 0x7FFFu + ((u >> 16) & 1u)) >> 16);
}

// ---------------------------------------------------------------------------
// Wh + e-partial producer body (K1 and kG<false>'s tail) — validated R12.
// Block (n,t,s) owns rows m = t*144 + s*9 + [0,9). Wh -> Whg[b*4608] bf16;
// e-partials -> ep[n][q=t][s][256].
// ---------------------------------------------------------------------------
__device__ __forceinline__ void wh_e_body(int n, int t, int s, int b,
                                          const float* __restrict__ xb,   // LDS
                                          float* __restrict__ red,        // LDS
                                          const float* __restrict__ mw_l,
                                          const float* __restrict__ mb_l,
                                          const float* __restrict__ a_l,
                                          unsigned short* __restrict__ Whg,
                                          float* __restrict__ ep) {
    int tid = threadIdx.x;
    int sub = tid >> 5, v = tid & 31;
    int hd = sub & 3, r0 = sub >> 2;
    unsigned short* Wb = Whg + (size_t)b * 4608;
    float ei = 0.f, ej = 0.f;
    for (int r = r0; r < 9; r += 4) {
        int rr = s * 9 + r;
        int dh = rr / 24, wc = rr % 24;
        const float* ab = a_l + hd * 1152 + dh * 192 + wc * 4;
        float4 aiv = *(const float4*)ab;
        float4 ajv = *(const float4*)(ab + 96);
        float x0 = xb[r * 128 + v],      x1 = xb[r * 128 + 32 + v];
        float x2 = xb[r * 128 + 64 + v], x3 = xb[r * 128 + 96 + v];
#pragma unroll
        for (int tt = 0; tt < 4; ++tt) {
            float wh = fmaf(x0, mw_l[hd * 16 + tt],
                        fmaf(x1, mw_l[hd * 16 + 4 + tt],
                         fmaf(x2, mw_l[hd * 16 + 8 + tt],
                          fmaf(x3, mw_l[hd * 16 + 12 + tt], mb_l[hd * 4 + tt]))));
            Wb[((hd * 4 + tt) * 9 + r) * 32 + v] = f2bf(wh);
            ei = fmaf(wh, (&aiv.x)[tt], ei);
            ej = fmaf(wh, (&ajv.x)[tt], ej);
        }
    }
    red[(sub * 2 + 0) * 32 + v] = ei;
    red[(sub * 2 + 1) * 32 + v] = ej;
    __syncthreads();
    if (tid < 256) {        // tid == hd*64 + wh*32 + v
        int hdx = tid >> 6, whx = (tid >> 5) & 1, vx = tid & 31;
        float e = 0.f;
#pragma unroll
        for (int k = 0; k < 4; ++k)
            e += red[((hdx + 4 * k) * 2 + whx) * 32 + vx];
        ep[(((size_t)(n * 4 + t)) * 16 + s) * 256 + tid] = e;
    }
}

// ---------------------------------------------------------------------------
// K1: stage x slice -> Wh(L0) + e-partials(L0).  (validated R12)
// ---------------------------------------------------------------------------
__global__ __launch_bounds__(NTHR) void k1(const float* __restrict__ x,
                                           const float* __restrict__ map_w,
                                           const float* __restrict__ map_b,
                                           const float* __restrict__ a_temp,
                                           unsigned short* __restrict__ Whg,
                                           float* __restrict__ ep0) {
    __shared__ float xb[1152];
    __shared__ float red[1024];
    int b = blockIdx.x, tid = threadIdx.x;
    int n = b >> 6, t = (b >> 4) & 3, s = b & 15;
    if (tid < 288)
        ((float4*)xb)[tid] =
            ((const float4*)(x + (size_t)(n * MM + t * 144 + s * 9) * 128))[tid];
    __syncthreads();
    wh_e_body(n, t, s, b, xb, red, map_w, map_b, a_temp, Whg, ep0);
}

// ---------------------------------------------------------------------------
// Single-wave adjacency build (fp32, shfl-based; validated structure).
// Row of val[k] is 2k+h; half-wave shfl sums give row sums.
// ---------------------------------------------------------------------------
__device__ __forceinline__ void adj_build_one(const float* __restrict__ B,
                                              float* __restrict__ adjf,
                                              float* __restrict__ d12s) {
    int lane = threadIdx.x & 63;
    int u = lane & 31;
    float val[16], lmin = 1e30f, lmax = -1e30f;
#pragma unroll
    for (int k = 0; k < 16; ++k) {
        int p = lane + 64 * k;
        float vv = B[p] + ((p >> 5) == (p & 31) ? 1.f : 0.f);
        val[k] = vv;
        lmin = fminf(lmin, vv);
        lmax = fmaxf(lmax, vv);
    }
#pragma unroll
    for (int off = 32; off; off >>= 1) {
        lmin = fminf(lmin, __shfl_xor(lmin, off, 64));
        lmax = fmaxf(lmax, __shfl_xor(lmax, off, 64));
    }
    float inv = 1.f / (lmax - lmin);
    float d12r[16];
    int h = lane >> 5;
#pragma unroll
    for (int k = 0; k < 16; ++k) {      // row sum of row 2k+h (half-wave)
        float r = val[k];
#pragma unroll
        for (int off = 16; off; off >>= 1) r += __shfl_xor(r, off, 64);
        float rsn = (r - 32.f * lmin) * inv;
        d12r[k] = rsqrtf(rsn);
        if (u == 2 * k + h) d12s[u] = d12r[k];
    }
#pragma unroll
    for (int k = 0; k < 16; ++k) {      // in-wave LDS write->read, ordered
        int p = lane + 64 * k;
        adjf[p] = (val[k] - lmin) * inv * d12r[k] * d12s[p & 31];
    }
}

// ---------------------------------------------------------------------------
// kC: 64 blocks = (n, hd, q). e-reduce -> adj(fp32) -> att^T(fp32, padded)
// -> C, stored TRANSPOSED to CT[n][hd][q][u][j] (fp32, global/L2).
// Computed once instead of 64x per n.
// ---------------------------------------------------------------------------
__global__ __launch_bounds__(256) void kC(const float* __restrict__ Bp_l,
                                          const float* __restrict__ ep,
                                          float* __restrict__ CT) {
    __shared__ float e[4][2][32];
    __shared__ float adjf[1024];
    __shared__ float attT[32 * 33];     // +1 pad: conflict-free column reads
    __shared__ float d12s[32];
    int b = blockIdx.x, tid = threadIdx.x;
    int n = b >> 4, hd = (b >> 2) & 3, q = b & 3;

    {   // e-reduce over 16 s-slices: thread -> (q', wh, v)
        int qp = tid >> 6, rest = tid & 63;
        const float* src = ep + ((size_t)(n * 4 + qp) * 16) * 256 + hd * 64 + rest;
        float a = 0.f;
#pragma unroll
        for (int ss = 0; ss < 16; ++ss) a += src[ss * 256];
        e[qp][rest >> 5][rest & 31] = a;
    }
    if (tid < 64) adj_build_one(Bp_l + (size_t)hd * 1024, adjf, d12s);
    __syncthreads();

    {   // att^T[j][i], softmax over q' keeping q
        int i = tid & 31;
        float ei0 = e[0][0][i], ei1 = e[1][0][i], ei2 = e[2][0][i], ei3 = e[3][0][i];
#pragma unroll
        for (int k = 0; k < 4; ++k) {
            int j = (tid + 256 * k) >> 5;
            float eq0 = lrelu(ei0 + e[0][1][j]);
            float eq1 = lrelu(ei1 + e[1][1][j]);
            float eq2 = lrelu(ei2 + e[2][1][j]);
            float eq3 = lrelu(ei3 + e[3][1][j]);
            float mx = fmaxf(fmaxf(eq0, eq1), fmaxf(eq2, eq3));
            eq0 = __expf(eq0 - mx); eq1 = __expf(eq1 - mx);
            eq2 = __expf(eq2 - mx); eq3 = __expf(eq3 - mx);
            float invs = __builtin_amdgcn_rcpf(eq0 + eq1 + eq2 + eq3);
            float num = (q & 2) ? ((q & 1) ? eq3 : eq2) : ((q & 1) ? eq1 : eq0);
            attT[j * 33 + i] = num * invs;
        }
    }
    __syncthreads();

    {   // CT[u][j4..j4+3] = C[j][u] = sum_i attT[j][i] * adjf[i][u]
        int u = tid >> 3, j4 = (tid & 7) * 4;
        float c0 = 0.f, c1 = 0.f, c2 = 0.f, c3 = 0.f;
#pragma unroll
        for (int i = 0; i < 32; ++i) {
            float ad = adjf[i * 32 + u];
            c0 = fmaf(attT[(j4 + 0) * 33 + i], ad, c0);
            c1 = fmaf(attT[(j4 + 1) * 33 + i], ad, c1);
            c2 = fmaf(attT[(j4 + 2) * 33 + i], ad, c2);
            c3 = fmaf(attT[(j4 + 3) * 33 + i], ad, c3);
        }
        float4 cv = make_float4(c0, c1, c2, c3);
        *(float4*)&CT[(((size_t)(n * 4 + hd) * 4 + q) * 32 + u) * 32 + j4] = cv;
    }
}

// ---------------------------------------------------------------------------
// kG: 256 blocks = (n,t,s). cc columns prefetched from CT (global float4),
// Whh copied to LDS, gemm + elu + head-mean. LAST ? out : (xb -> layer-2
// Wh + e-partials via wh_e_body, block-local).
// ---------------------------------------------------------------------------
template<bool LAST>
__device__ __forceinline__ void kG_body(const float* __restrict__ CT,
                                        unsigned short* __restrict__ Whg,
                                        const float* __restrict__ mw2,
                                        const float* __restrict__ mb2,
                                        const float* __restrict__ a2,
                                        float* __restrict__ ep_out,
                                        float* __restrict__ outg) {
    __shared__ unsigned short Whh[4][4][9][32];   // 9216 B
    __shared__ float uf[3584];  // [0,1152) xb | [1216,2240) red | [2304,3584) partials
    int b = blockIdx.x, tid = threadIdx.x;
    int n = b >> 6, t = (b >> 4) & 3, s = b & 15;
    int w = tid >> 6, lane = tid & 63;
    int g = w >> 2, tout = w & 3;
    int u = lane & 31, h = lane >> 5;

    // prefetch C columns for both hd of this wave's group (overlaps copy)
    float cc0[32], cc1[32];
    const float4* ct0 = (const float4*)(CT + (((size_t)(n * 4 + 2 * g) * 4 + tout) * 32 + u) * 32);
    const float4* ct1 = (const float4*)(CT + (((size_t)(n * 4 + 2 * g + 1) * 4 + tout) * 32 + u) * 32);
#pragma unroll
    for (int k = 0; k < 8; ++k) *(float4*)&cc0[4 * k] = ct0[k];
    {   // Whh copy: 2304 u32
        const unsigned* src = (const unsigned*)(Whg + (size_t)b * 4608);
        unsigned* dst = (unsigned*)&Whh[0][0][0][0];
#pragma unroll
        for (int k = 0; k < 4; ++k) dst[tid + 512 * k] = src[tid + 512 * k];
        if (tid < 256) dst[tid + 2048] = src[tid + 2048];
    }
#pragma unroll
    for (int k = 0; k < 8; ++k) *(float4*)&cc1[4 * k] = ct1[k];
    __syncthreads();

    float acc[5] = {0.f, 0.f, 0.f, 0.f, 0.f};
    auto gemm_hd = [&](int hd, const float (&cc)[32]) {
#pragma unroll
        for (int k = 0; k < 5; ++k) {
            int r = h ? (k < 4 ? 5 + k : 8) : k;   // k==4,h==1 discarded
            const uint4* wr = (const uint4*)&Whh[hd][tout][r][0];
            float d = 0.f;
#pragma unroll
            for (int q4 = 0; q4 < 4; ++q4) {
                uint4 pk = wr[q4];
                d = fmaf(__uint_as_float(pk.x << 16),         cc[8 * q4 + 0], d);
                d = fmaf(__uint_as_float(pk.x & 0xFFFF0000u), cc[8 * q4 + 1], d);
                d = fmaf(__uint_as_float(pk.y << 16),         cc[8 * q4 + 2], d);
                d = fmaf(__uint_as_float(pk.y & 0xFFFF0000u), cc[8 * q4 + 3], d);
                d = fmaf(__uint_as_float(pk.z << 16),         cc[8 * q4 + 4], d);
                d = fmaf(__uint_as_float(pk.z & 0xFFFF0000u), cc[8 * q4 + 5], d);
                d = fmaf(__uint_as_float(pk.w << 16),         cc[8 * q4 + 6], d);
                d = fmaf(__uint_as_float(pk.w & 0xFFFF0000u), cc[8 * q4 + 7], d);
            }
            acc[k] += elu1(d);
        }
    };
    gemm_hd(2 * g,     cc0);
    gemm_hd(2 * g + 1, cc1);

    if (g == 1) {       // publish partials
        float* part = uf + 2304 + tout * 320;
#pragma unroll
        for (int k = 0; k < 5; ++k)
            if (h == 0 || k < 4) part[k * 64 + lane] = acc[k];
    }
    __syncthreads();
    if (g == 0) {
        const float* part = uf + 2304 + tout * 320;
#pragma unroll
        for (int k = 0; k < 5; ++k)
            if (h == 0 || k < 4) acc[k] += part[k * 64 + lane];
        if (LAST) {
            size_t mb = (size_t)(n * MM + t * 144 + s * 9);
#pragma unroll
            for (int k = 0; k < 5; ++k) {
                if (h == 0 || k < 4) {
                    int r = h ? 5 + k : k;
                    outg[((mb + r) * 4 + tout) * 32 + u] = 0.25f * acc[k];
                }
            }
        } else {
            float* xb = uf;
#pragma unroll
            for (int k = 0; k < 5; ++k) {
                if (h == 0 || k < 4) {
                    int r = h ? 5 + k : k;
                    xb[r * 128 + tout * 32 + u] = 0.25f * acc[k];
                }
            }
        }
    }

    if (!LAST) {        // layer-2 producer, block-local
        __syncthreads();    // xb complete
        wh_e_body(n, t, s, b, uf, uf + 1216, mw2, mb2, a2, Whg, ep_out);
    }
}

__global__ __launch_bounds__(NTHR) void kG0(const float* __restrict__ CT,
                                            unsigned short* __restrict__ Whg,
                                            const float* __restrict__ mw2,
                                            const float* __restrict__ mb2,
                                            const float* __restrict__ a2,
                                            float* __restrict__ ep1) {
    kG_body<false>(CT, Whg, mw2, mb2, a2, ep1, nullptr);
}

__global__ __launch_bounds__(NTHR) void kG1(const float* __restrict__ CT,
                                            unsigned short* __restrict__ Whg,
                                            float* __restrict__ outg) {
    kG_body<true>(CT, Whg, nullptr, nullptr, nullptr, nullptr, outg);
}

// ---------------------------------------------------------------------------
extern "C" void kernel_launch(void* const* d_in, const int* in_sizes, int n_in,
                              void* d_out, int out_size, void* d_ws, size_t ws_size,
                              hipStream_t stream) {
    const float* x      = (const float*)d_in[0];
    const float* map_w  = (const float*)d_in[1];
    const float* map_b  = (const float*)d_in[2];
    const float* a_temp = (const float*)d_in[3];
    const float* Bp     = (const float*)d_in[4];
    float* out = (float*)d_out;

    unsigned short* Whg = (unsigned short*)d_ws;            // 2,359,296 B
    float* ep0 = (float*)((char*)d_ws + 2359296);           // 65536 f
    float* ep1 = ep0 + 65536;                               // 65536 f
    float* CT0 = ep1 + 65536;                               // 65536 f
    float* CT1 = CT0 + 65536;                               // 65536 f
    // Every byte of Whg/ep0/ep1/CT0/CT1 is overwritten before it is read
    // each call: no memset, no atomics — coherence via kernel boundaries.

    k1 <<<NBLK, NTHR, 0, stream>>>(x, map_w, map_b, a_temp, Whg, ep0);
    kC <<<64, 256, 0, stream>>>(Bp, ep0, CT0);
    kG0<<<NBLK, NTHR, 0, stream>>>(CT0, Whg, map_w + 64, map_b + 16,
                                   a_temp + 4608, ep1);
    kC <<<64, 256, 0, stream>>>(Bp + 4096, ep1, CT1);
    kG1<<<NBLK, NTHR, 0, stream>>>(CT1, Whg, out);
}